// Round 1
// baseline (293.553 us; speedup 1.0000x reference)
//
#include <hip/hip_runtime.h>

#define HID   2048
#define NE    64
#define TM    64
#define KC    64
#define LSTR  65          // LDS row stride (pad) -> conflict-free writes/reads
#define BATCH 4
#define SEQ   4096
#define CAP   128

// ---------------------------------------------------------------------------
// Kernel 1: router GEMM (fp32 vector) + bias + logits store + softmax stats
//           (argmax + max-prob) + zero the expert_indices tile.
// Block: 256 threads (4 waves). Tile: 64 tokens x 64 experts. Grid: 256.
// Thread (q = tid&15, r = tid>>4) owns tokens r*4..r*4+3, experts q*4..q*4+3.
// A token's 64 experts live in 16 consecutive lanes of ONE wave -> shuffle
// reduction for softmax stats, no LDS round trip.
// ---------------------------------------------------------------------------
__global__ __launch_bounds__(256, 4) void router_gemm_kernel(
    const float* __restrict__ x,       // (B*S, HID)
    const float* __restrict__ W,       // (NE, HID)
    const float* __restrict__ bias,    // (NE)
    float* __restrict__ out_ind,       // (B*S, NE)  zeroed here, 1.0s later
    float* __restrict__ out_probs,     // (B*S)
    float* __restrict__ logits_out,    // (B*S, NE)
    int* __restrict__ eidx)            // (B*S) workspace: argmax expert
{
    __shared__ float xs[KC * LSTR];    // xs[k][token]
    __shared__ float ws[KC * LSTR];    // ws[k][expert]

    const int tid = threadIdx.x;
    const int q   = tid & 15;          // expert group (e0 = q*4)
    const int r   = tid >> 4;          // token group  (t0 = r*4)
    const int m0  = blockIdx.x * TM;

    float acc[4][4];
#pragma unroll
    for (int a = 0; a < 4; ++a)
#pragma unroll
        for (int b2 = 0; b2 < 4; ++b2) acc[a][b2] = 0.f;

    for (int kc = 0; kc < HID; kc += KC) {
        // ---- stage x and W tiles, transposed, into LDS ----
#pragma unroll
        for (int j = 0; j < 4; ++j) {
            const int row = r + j * 16;          // token / expert row 0..63
            const float4 xv = *(const float4*)(x + (size_t)(m0 + row) * HID + kc + q * 4);
            const float4 wv = *(const float4*)(W + (size_t)row * HID + kc + q * 4);
            const int kb = q * 4;
            xs[(kb + 0) * LSTR + row] = xv.x;
            xs[(kb + 1) * LSTR + row] = xv.y;
            xs[(kb + 2) * LSTR + row] = xv.z;
            xs[(kb + 3) * LSTR + row] = xv.w;
            ws[(kb + 0) * LSTR + row] = wv.x;
            ws[(kb + 1) * LSTR + row] = wv.y;
            ws[(kb + 2) * LSTR + row] = wv.z;
            ws[(kb + 3) * LSTR + row] = wv.w;
        }
        __syncthreads();

        // ---- inner product over this K chunk ----
#pragma unroll 8
        for (int k = 0; k < KC; ++k) {
            float xv[4], wv[4];
#pragma unroll
            for (int i = 0; i < 4; ++i) xv[i] = xs[k * LSTR + r * 4 + i];
#pragma unroll
            for (int i = 0; i < 4; ++i) wv[i] = ws[k * LSTR + q * 4 + i];
#pragma unroll
            for (int a = 0; a < 4; ++a)
#pragma unroll
                for (int b2 = 0; b2 < 4; ++b2)
                    acc[a][b2] += xv[a] * wv[b2];
        }
        __syncthreads();
    }

    // ---- epilogue: bias, logits store, softmax stats per token ----
    const float4 bv = ((const float4*)bias)[q];
    float l[4][4];
#pragma unroll
    for (int a = 0; a < 4; ++a) {
        l[a][0] = acc[a][0] + bv.x;
        l[a][1] = acc[a][1] + bv.y;
        l[a][2] = acc[a][2] + bv.z;
        l[a][3] = acc[a][3] + bv.w;
        float4 st = make_float4(l[a][0], l[a][1], l[a][2], l[a][3]);
        *(float4*)(logits_out + (size_t)(m0 + r * 4 + a) * NE + q * 4) = st;
    }

#pragma unroll
    for (int a = 0; a < 4; ++a) {
        // local argmax over my 4 experts (strict > keeps first occurrence)
        float v = l[a][0];
        int   bi = q * 4;
#pragma unroll
        for (int b2 = 1; b2 < 4; ++b2) {
            if (l[a][b2] > v) { v = l[a][b2]; bi = q * 4 + b2; }
        }
        // merge across the 16 lanes that hold this token (xor 1,2,4,8)
#pragma unroll
        for (int mm = 1; mm <= 8; mm <<= 1) {
            float ov = __shfl_xor(v, mm);
            int   oi = __shfl_xor(bi, mm);
            if (ov > v || (ov == v && oi < bi)) { v = ov; bi = oi; }
        }
        // sum of exp(l - max)
        float s = 0.f;
#pragma unroll
        for (int b2 = 0; b2 < 4; ++b2) s += __expf(l[a][b2] - v);
#pragma unroll
        for (int mm = 1; mm <= 8; mm <<= 1) s += __shfl_xor(s, mm);

        if (q == 0) {
            const int tok = m0 + r * 4 + a;
            out_probs[tok] = 1.f / s;   // max prob = exp(max-max)/sum
            eidx[tok]      = bi;
        }
    }

    // ---- zero this block's expert_indices slice (scatter kernel fills 1s) --
    const float4 z4 = make_float4(0.f, 0.f, 0.f, 0.f);
    float4* oz = (float4*)(out_ind + (size_t)m0 * NE);
#pragma unroll
    for (int j = 0; j < 4; ++j) oz[tid + j * 256] = z4;
}

// ---------------------------------------------------------------------------
// Kernel 2: capacity scan. One wave per (batch, expert). Inclusive cumsum of
// one_hot over the sequence via ballot + prefix popcount; write 1.0 where
// rank <= CAP. Grid: 64 blocks x 256 threads = 256 waves = 4 batches x 64 e.
// ---------------------------------------------------------------------------
__global__ __launch_bounds__(256) void capacity_kernel(
    const int* __restrict__ eidx, float* __restrict__ out_ind)
{
    const int wid  = (blockIdx.x * blockDim.x + threadIdx.x) >> 6; // 0..255
    const int lane = threadIdx.x & 63;
    const int b    = wid >> 6;     // batch 0..3
    const int e    = wid & 63;     // expert 0..63

    const int* row = eidx + (size_t)b * SEQ;
    int run = 0;
    for (int s0 = 0; s0 < SEQ; s0 += 64) {
        const int idx = row[s0 + lane];
        const unsigned long long m = __ballot(idx == e);
        const int pre = __popcll(m & ((1ull << lane) - 1ull));
        if (idx == e) {
            const int rank = run + pre + 1;   // inclusive cumsum
            if (rank <= CAP)
                out_ind[((size_t)b * SEQ + s0 + lane) * NE + e] = 1.0f;
        }
        run += __popcll(m);
    }
}

// ---------------------------------------------------------------------------
extern "C" void kernel_launch(void* const* d_in, const int* in_sizes, int n_in,
                              void* d_out, int out_size, void* d_ws, size_t ws_size,
                              hipStream_t stream)
{
    const float* x    = (const float*)d_in[0];   // (4,4096,2048)
    const float* W    = (const float*)d_in[1];   // (64,2048)
    const float* bias = (const float*)d_in[2];   // (64)

    float* out_ind   = (float*)d_out;                              // B*S*NE
    float* out_probs = out_ind + (size_t)BATCH * SEQ * NE;         // B*S
    float* logits    = out_probs + (size_t)BATCH * SEQ;            // B*S*NE
    int*   eidx      = (int*)d_ws;                                 // B*S ints

    router_gemm_kernel<<<(BATCH * SEQ) / TM, 256, 0, stream>>>(
        x, W, bias, out_ind, out_probs, logits, eidx);
    capacity_kernel<<<64, 256, 0, stream>>>(eidx, out_ind);
}

// Round 3
// 236.163 us; speedup vs baseline: 1.2430x; 1.2430x over previous
//
#include <hip/hip_runtime.h>
#include <stdint.h>

#define HID   2048
#define NE    64
#define BATCH 4
#define SEQ   4096
#define CAP   128
#define TM    64                 // tokens per block
#define KC    64                 // k per chunk
#define NCHUNK (HID / KC)        // 32
#define PLANE  8192              // 64 rows x 128 bytes (64 k x 2B) per bf16 plane
#define ROWB   128

typedef __attribute__((ext_vector_type(8))) short s16x8;   // 8 bf16 = 4 VGPR
typedef __attribute__((ext_vector_type(4))) float f32x4;

// XOR swizzle on the 16B-slot index within a 128B row; bijective per row.
// Verified bank math: both ds_write_b128 staging and ds_read_b128 fragment
// reads hit all 32 banks uniformly (8 dwords/bank per wave op).
__device__ __forceinline__ int swz(int row, int kb) {
    return row * ROWB + (kb ^ (((row ^ (row >> 3)) & 7) << 4));
}

// Exact 3-term bf16 bit-slice: v = h0 + h1 + h2 exactly (8+8+8 >= 24 mantissa
// bits, truncation slicing; residual after two subtractions has <= 8 bits).
__device__ __forceinline__ void split1(float v, unsigned& b0, unsigned& b1, unsigned& b2) {
    unsigned b = __float_as_uint(v);
    b0 = b & 0xffff0000u;
    float r1 = v - __uint_as_float(b0);
    unsigned c = __float_as_uint(r1);
    b1 = c & 0xffff0000u;
    float r2 = r1 - __uint_as_float(b1);
    b2 = __float_as_uint(r2) & 0xffff0000u;
}

// pack 8 consecutive fp32 (ascending k) -> 3 planes x uint4 (8 bf16 each)
__device__ __forceinline__ void pack8(const float f[8], uint4& p0, uint4& p1, uint4& p2) {
    unsigned q0[4], q1[4], q2[4];
#pragma unroll
    for (int j = 0; j < 4; ++j) {
        unsigned a0, a1, a2, c0, c1, c2;
        split1(f[2 * j],     a0, a1, a2);
        split1(f[2 * j + 1], c0, c1, c2);
        q0[j] = (a0 >> 16) | c0;      // low16 = even k, high16 = odd k
        q1[j] = (a1 >> 16) | c1;
        q2[j] = (a2 >> 16) | c2;
    }
    p0 = make_uint4(q0[0], q0[1], q0[2], q0[3]);
    p1 = make_uint4(q1[0], q1[1], q1[2], q1[3]);
    p2 = make_uint4(q2[0], q2[1], q2[2], q2[3]);
}

// ---------------------------------------------------------------------------
// Router GEMM via bf16x3-split MFMA (6 passes: 00,01,10,02,11,20 -> fp32-exact
// to ~2^-24 rel), fused bias + logits + softmax stats + out_ind zeroing.
// 256 blocks x 256 threads (4 waves, 2x2 wave grid). Tile 64 tok x 64 exp,
// KC=64, double-buffered 96 KiB LDS, one barrier per chunk, loads issued early.
// ---------------------------------------------------------------------------
__global__ __launch_bounds__(256, 1) void router_mfma_kernel(
    const float* __restrict__ x,       // (B*S, HID)
    const float* __restrict__ W,       // (NE, HID)
    const float* __restrict__ bias,    // (NE)
    float* __restrict__ out_ind,       // (B*S, NE) zeroed here
    float* __restrict__ out_probs,     // (B*S)
    float* __restrict__ logits_out,    // (B*S, NE)
    int* __restrict__ eidx)            // (B*S) ws: argmax expert
{
    __shared__ __align__(16) char smem[2 * 6 * PLANE];   // 96 KiB

    const int tid  = threadIdx.x;
    const int m0   = blockIdx.x * TM;
    const int w    = tid >> 6;          // wave 0..3
    const int wr2  = w >> 1;            // token half (32 rows)
    const int wc   = w & 1;             // expert half (32 cols)
    const int lane = tid & 63;
    const int l15  = lane & 15;
    const int l4   = lane >> 4;

    // staging role: row 0..63, k-quarter sg (16 floats)
    const int srow = tid >> 2;
    const int sg   = tid & 3;

    float bv[2];
#pragma unroll
    for (int t = 0; t < 2; ++t) bv[t] = bias[32 * wc + 16 * t + l15];

    f32x4 acc[2][2];
#pragma unroll
    for (int a = 0; a < 2; ++a)
#pragma unroll
        for (int t = 0; t < 2; ++t) acc[a][t] = (f32x4){0.f, 0.f, 0.f, 0.f};

    float4 xr[4], wr[4];
    auto stage_load = [&](int c) {
        const float* xp = x + (size_t)(m0 + srow) * HID + c * KC + sg * 16;
        const float* wp = W + (size_t)srow * HID + c * KC + sg * 16;
#pragma unroll
        for (int i = 0; i < 4; ++i) { xr[i] = ((const float4*)xp)[i]; wr[i] = ((const float4*)wp)[i]; }
    };
    auto stage_write = [&](int buf) {
        char* bb = smem + buf * 6 * PLANE;
#pragma unroll
        for (int gi = 0; gi < 2; ++gi) {
            const int off = swz(srow, sg * 32 + gi * 16);
            float f[8];
            uint4 p0, p1, p2;
            f[0]=xr[2*gi].x; f[1]=xr[2*gi].y; f[2]=xr[2*gi].z; f[3]=xr[2*gi].w;
            f[4]=xr[2*gi+1].x; f[5]=xr[2*gi+1].y; f[6]=xr[2*gi+1].z; f[7]=xr[2*gi+1].w;
            pack8(f, p0, p1, p2);
            *(uint4*)(bb + 0 * PLANE + off) = p0;
            *(uint4*)(bb + 1 * PLANE + off) = p1;
            *(uint4*)(bb + 2 * PLANE + off) = p2;
            f[0]=wr[2*gi].x; f[1]=wr[2*gi].y; f[2]=wr[2*gi].z; f[3]=wr[2*gi].w;
            f[4]=wr[2*gi+1].x; f[5]=wr[2*gi+1].y; f[6]=wr[2*gi+1].z; f[7]=wr[2*gi+1].w;
            pack8(f, p0, p1, p2);
            *(uint4*)(bb + 3 * PLANE + off) = p0;
            *(uint4*)(bb + 4 * PLANE + off) = p1;
            *(uint4*)(bb + 5 * PLANE + off) = p2;
        }
    };

    // prologue
    stage_load(0);
    stage_write(0);
    __syncthreads();

#pragma unroll 1
    for (int c = 0; c < NCHUNK; ++c) {
        if (c + 1 < NCHUNK) stage_load(c + 1);     // issue early (T14)

        const char* base = smem + (c & 1) * 6 * PLANE;
#pragma unroll
        for (int ks = 0; ks < 2; ++ks) {
            const int kb = ks * 64 + l4 * 16;
            s16x8 a[2][3], b[2][3];
#pragma unroll
            for (int ai = 0; ai < 2; ++ai) {
                const int off = swz(32 * wr2 + 16 * ai + l15, kb);
                a[ai][0] = *(const s16x8*)(base + 0 * PLANE + off);
                a[ai][1] = *(const s16x8*)(base + 1 * PLANE + off);
                a[ai][2] = *(const s16x8*)(base + 2 * PLANE + off);
            }
#pragma unroll
            for (int t = 0; t < 2; ++t) {
                const int off = swz(32 * wc + 16 * t + l15, kb);
                b[t][0] = *(const s16x8*)(base + 3 * PLANE + off);
                b[t][1] = *(const s16x8*)(base + 4 * PLANE + off);
                b[t][2] = *(const s16x8*)(base + 5 * PLANE + off);
            }
#pragma unroll
            for (int ai = 0; ai < 2; ++ai)
#pragma unroll
                for (int t = 0; t < 2; ++t) {
                    acc[ai][t] = __builtin_amdgcn_mfma_f32_16x16x32_bf16(a[ai][0], b[t][0], acc[ai][t], 0, 0, 0);
                    acc[ai][t] = __builtin_amdgcn_mfma_f32_16x16x32_bf16(a[ai][0], b[t][1], acc[ai][t], 0, 0, 0);
                    acc[ai][t] = __builtin_amdgcn_mfma_f32_16x16x32_bf16(a[ai][1], b[t][0], acc[ai][t], 0, 0, 0);
                    acc[ai][t] = __builtin_amdgcn_mfma_f32_16x16x32_bf16(a[ai][0], b[t][2], acc[ai][t], 0, 0, 0);
                    acc[ai][t] = __builtin_amdgcn_mfma_f32_16x16x32_bf16(a[ai][1], b[t][1], acc[ai][t], 0, 0, 0);
                    acc[ai][t] = __builtin_amdgcn_mfma_f32_16x16x32_bf16(a[ai][2], b[t][0], acc[ai][t], 0, 0, 0);
                }
        }

        if (c + 1 < NCHUNK) stage_write((c + 1) & 1);
        __syncthreads();
    }

    // ---- epilogue: bounce logits through LDS [64][68] ----
    float* lg = (float*)smem;
    // C/D layout 16x16x32 (m89-verified): col = lane&15, row = (lane>>4)*4+reg
#pragma unroll
    for (int ai = 0; ai < 2; ++ai)
#pragma unroll
        for (int t = 0; t < 2; ++t)
#pragma unroll
            for (int rr = 0; rr < 4; ++rr) {
                const int tokb = 32 * wr2 + 16 * ai + 4 * l4 + rr;
                lg[tokb * 68 + 32 * wc + 16 * t + l15] = acc[ai][t][rr] + bv[t];
            }
    __syncthreads();

    // stats: 4 threads per token, 16 experts each
    {
        const int tok = tid >> 2, t4 = tid & 3;
        float vals[16];
#pragma unroll
        for (int i = 0; i < 4; ++i) {
            float4 v = *(const float4*)&lg[tok * 68 + t4 * 16 + 4 * i];
            vals[4 * i] = v.x; vals[4 * i + 1] = v.y; vals[4 * i + 2] = v.z; vals[4 * i + 3] = v.w;
        }
        float m = vals[0];
        int mi = t4 * 16;
#pragma unroll
        for (int j = 1; j < 16; ++j)
            if (vals[j] > m) { m = vals[j]; mi = t4 * 16 + j; }
#pragma unroll
        for (int mm = 1; mm <= 2; mm <<= 1) {
            float om = __shfl_xor(m, mm);
            int   oi = __shfl_xor(mi, mm);
            if (om > m || (om == m && oi < mi)) { m = om; mi = oi; }
        }
        float s = 0.f;
#pragma unroll
        for (int j = 0; j < 16; ++j) s += __expf(vals[j] - m);
#pragma unroll
        for (int mm = 1; mm <= 2; mm <<= 1) s += __shfl_xor(s, mm);
        if (t4 == 0) {
            out_probs[m0 + tok] = 1.f / s;   // max prob = 1/sum(exp(l-max))
            eidx[m0 + tok] = mi;
        }
    }

    // coalesced logits store + zero expert_indices slice
    {
        float4* lout = (float4*)(logits_out + (size_t)m0 * NE);
        float4* oz   = (float4*)(out_ind + (size_t)m0 * NE);
        const float4 z4 = make_float4(0.f, 0.f, 0.f, 0.f);
#pragma unroll
        for (int i = 0; i < 4; ++i) {
            const int fi = tid + 256 * i;            // 1024 float4 total
            const int row = fi >> 4, c4 = fi & 15;
            lout[fi] = *(const float4*)&lg[row * 68 + c4 * 4];
            oz[fi] = z4;
        }
    }
}

// ---------------------------------------------------------------------------
// Capacity scan: 1 wave per (batch, expert), 256 blocks. Ballot + prefix
// popcount inclusive cumsum over the sequence; write 1.0 where rank <= CAP.
// ---------------------------------------------------------------------------
__device__ __forceinline__ void cap_step(int v, int e, int lane, int s_abs,
                                         float* col, int& run) {
    const unsigned long long mm = __ballot(v == e);
    if (v == e) {
        const int rank = run + __popcll(mm & ((1ull << lane) - 1ull)) + 1;
        if (rank <= CAP) col[(size_t)(s_abs + lane) * NE] = 1.0f;
    }
    run += __popcll(mm);
}

__global__ __launch_bounds__(64) void capacity_kernel(
    const int* __restrict__ eidx, float* __restrict__ out_ind)
{
    const int lane = threadIdx.x;
    const int b = blockIdx.x >> 6;
    const int e = blockIdx.x & 63;
    const int* row = eidx + (size_t)b * SEQ;
    float* col = out_ind + (size_t)b * SEQ * NE + e;
    int run = 0;
    for (int s0 = 0; s0 < SEQ; s0 += 256) {
        const int v0 = row[s0 + lane];
        const int v1 = row[s0 + 64 + lane];
        const int v2 = row[s0 + 128 + lane];
        const int v3 = row[s0 + 192 + lane];
        cap_step(v0, e, lane, s0, col, run);
        cap_step(v1, e, lane, s0 + 64, col, run);
        cap_step(v2, e, lane, s0 + 128, col, run);
        cap_step(v3, e, lane, s0 + 192, col, run);
    }
}

// ---------------------------------------------------------------------------
extern "C" void kernel_launch(void* const* d_in, const int* in_sizes, int n_in,
                              void* d_out, int out_size, void* d_ws, size_t ws_size,
                              hipStream_t stream)
{
    const float* x    = (const float*)d_in[0];
    const float* W    = (const float*)d_in[1];
    const float* bias = (const float*)d_in[2];

    float* out_ind   = (float*)d_out;
    float* out_probs = out_ind + (size_t)BATCH * SEQ * NE;
    float* logits    = out_probs + (size_t)BATCH * SEQ;
    int*   eidx      = (int*)d_ws;

    router_mfma_kernel<<<(BATCH * SEQ) / TM, 256, 0, stream>>>(
        x, W, bias, out_ind, out_probs, logits, eidx);
    capacity_kernel<<<BATCH * NE, 64, 0, stream>>>(eidx, out_ind);
}